// Round 4
// baseline (873.942 us; speedup 1.0000x reference)
//
#include <hip/hip_runtime.h>
#include <cstddef>
#include <cstdint>

#define B_ 64
#define T_ 512
#define C_ 384
#define H_ 6
#define HD_ 64
#define FF_ 1536

typedef unsigned short u16;
typedef unsigned int u32;
typedef __attribute__((ext_vector_type(8))) __bf16 bf16x8;
typedef __attribute__((ext_vector_type(8))) short short8;
typedef __attribute__((ext_vector_type(4))) float f32x4;

#define MFMA_BF16(a, b, c) __builtin_amdgcn_mfma_f32_16x16x32_bf16((a), (b), (c), 0, 0, 0)

__device__ __forceinline__ u16 f2bf(float f) {
    union { float f; unsigned u; } x; x.f = f;
    unsigned r = x.u + 0x7fff + ((x.u >> 16) & 1);   // RTNE
    return (u16)(r >> 16);
}

__device__ __forceinline__ void gload16(const u16* g, u16* l) {
    __builtin_amdgcn_global_load_lds(
        (const __attribute__((address_space(1))) void*)g,
        (__attribute__((address_space(3))) void*)l, 16, 0, 0);
}

// chunk swizzle for 64B-row LDS tiles (32 bf16/row, 4x16B chunks):
// LDS[row][ch] holds global[row][ch ^ ((row>>1)&3)] -> reads spread over 8 bank-slots
__device__ __forceinline__ int swz4(int row, int ch) { return ch ^ ((row >> 1) & 3); }

// ---------------------------------------------------------------------------
// prep: cast + transpose weights to bf16 [N][K], concat qkv biases, trig table
// ---------------------------------------------------------------------------
__global__ __launch_bounds__(256)
void prep_kernel(const float* __restrict__ q1w, const float* __restrict__ k1w, const float* __restrict__ v1w,
                 const float* __restrict__ q2w, const float* __restrict__ k2w, const float* __restrict__ v2w,
                 const float* __restrict__ p1w, const float* __restrict__ p2w,
                 const float* __restrict__ f1w, const float* __restrict__ f2w,
                 const float* __restrict__ q1b, const float* __restrict__ k1b, const float* __restrict__ v1b,
                 const float* __restrict__ q2b, const float* __restrict__ k2b, const float* __restrict__ v2b,
                 u16* wq1, u16* wq2, u16* p1t, u16* p2t, u16* f1t, u16* f2t,
                 float* bq1, float* bq2, float* cst, float* snt)
{
    const int job = blockIdx.y;
    const int idx = blockIdx.x * 256 + threadIdx.x;
    if (job <= 1) {                       // qkv: [n=1152][k=384], n = which*384+h*64+d
        if (idx >= 1152 * 384) return;
        const int n = idx / 384, k = idx - n * 384;
        const int wsel = n / 384;
        const int rest = n - wsel * 384;
        const int h = rest >> 6, d = rest & 63;
        const float* src;
        if (job == 0) src = (wsel == 0 ? q1w : wsel == 1 ? k1w : v1w);
        else          src = (wsel == 0 ? q2w : wsel == 1 ? k2w : v2w);
        (job == 0 ? wq1 : wq2)[idx] = f2bf(src[((size_t)h * 384 + k) * 64 + d]);
    } else if (job <= 3) {                // proj: [n=384][k=384] = pw[k][n]
        if (idx >= 384 * 384) return;
        const int n = idx / 384, k = idx - n * 384;
        const float* src = (job == 2 ? p1w : p2w);
        (job == 2 ? p1t : p2t)[idx] = f2bf(src[(size_t)k * 384 + n]);
    } else if (job == 4) {                // f1: [n=1536][k=384]
        if (idx >= 1536 * 384) return;
        const int n = idx / 384, k = idx - n * 384;
        f1t[idx] = f2bf(f1w[(size_t)k * 1536 + n]);
    } else if (job == 5) {                // f2: [n=384][k=1536]
        if (idx >= 384 * 1536) return;
        const int n = idx / 1536, k = idx - n * 1536;
        f2t[idx] = f2bf(f2w[(size_t)k * 384 + n]);
    } else {
        if (idx < 1152) {
            const int wsel = idx / 384, r = idx - wsel * 384;
            bq1[idx] = (wsel == 0 ? q1b : wsel == 1 ? k1b : v1b)[r];
        } else if (idx < 2304) {
            const int j = idx - 1152;
            const int wsel = j / 384, r = j - wsel * 384;
            bq2[j] = (wsel == 0 ? q2b : wsel == 1 ? k2b : v2b)[r];
        } else if (idx < 2816) {
            const int t = idx - 2304; cst[t] = cosf((float)t);
        } else if (idx < 3328) {
            const int t = idx - 2816; snt[t] = sinf((float)t);
        }
    }
}

// ---------------------------------------------------------------------------
__global__ __launch_bounds__(256)
void cast_kernel(const float* __restrict__ in, u16* __restrict__ out, int n4)
{
    int i = blockIdx.x * 256 + threadIdx.x;
    const int stride = gridDim.x * 256;
    for (; i < n4; i += stride) {
        float4 v = *reinterpret_cast<const float4*>(&in[(size_t)i * 4]);
        ushort4 o;
        o.x = f2bf(v.x); o.y = f2bf(v.y); o.z = f2bf(v.z); o.w = f2bf(v.w);
        *reinterpret_cast<ushort4*>(&out[(size_t)i * 4]) = o;
    }
}

// ---------------------------------------------------------------------------
// bf16 MFMA GEMM, tile 128x128, BK=32, 4 waves (2x2), 4x4 frags/wave.
// A [M][K], Bt [N][K] bf16.  Swizzled LDS staging (conflict-free reads).
// EPI 0: QKV (bias + RoPE for q,k; scatter to q/k/v [b,h,t,d] bf16)
// EPI 2: outb = relu(acc + bias[n])  (bf16, paired u32 stores)
// ---------------------------------------------------------------------------
template<int EPI>
__global__ __launch_bounds__(256)
void gemm_mfma(const u16* __restrict__ A, const u16* __restrict__ Bt, int K,
               const float* __restrict__ bias,
               u16* __restrict__ outb,
               u16* __restrict__ qo, u16* __restrict__ ko, u16* __restrict__ vo,
               const float* __restrict__ cst, const float* __restrict__ snt,
               int N)
{
    __shared__ u16 As[128 * 32];
    __shared__ u16 Bs[128 * 32];
    const int tid = threadIdx.x;
    const int w = tid >> 6, lane = tid & 63;
    const int m0 = blockIdx.x * 128, n0 = blockIdx.y * 128;
    const int wm = w >> 1, wn = w & 1;
    const int c = lane & 15, g = lane >> 4;
    const int cs = (c >> 1) & 3;

    const int srow = w * 16 + (lane >> 2);            // 0..63
    const u16* gA = A + (size_t)(m0 + srow) * K + swz4(srow, lane & 3) * 8;
    const u16* gB = Bt + (size_t)(n0 + srow) * K + swz4(srow, lane & 3) * 8;
    u16* lA = As + w * 512;
    u16* lB = Bs + w * 512;

    f32x4 acc[4][4];
    #pragma unroll
    for (int i = 0; i < 4; ++i)
        #pragma unroll
        for (int j = 0; j < 4; ++j) acc[i][j] = (f32x4)0.0f;

    for (int k0 = 0; k0 < K; k0 += 32) {
        __syncthreads();
        gload16(gA + k0, lA);
        gload16(gA + k0 + (size_t)64 * K, lA + 64 * 32);
        gload16(gB + k0, lB);
        gload16(gB + k0 + (size_t)64 * K, lB + 64 * 32);
        __syncthreads();
        bf16x8 af[4], bfr[4];
        #pragma unroll
        for (int fi = 0; fi < 4; ++fi)
            af[fi] = *(const bf16x8*)&As[(wm * 64 + fi * 16 + c) * 32 + (g ^ cs) * 8];
        #pragma unroll
        for (int fj = 0; fj < 4; ++fj)
            bfr[fj] = *(const bf16x8*)&Bs[(wn * 64 + fj * 16 + c) * 32 + (g ^ cs) * 8];
        #pragma unroll
        for (int fi = 0; fi < 4; ++fi)
            #pragma unroll
            for (int fj = 0; fj < 4; ++fj)
                acc[fi][fj] = MFMA_BF16(af[fi], bfr[fj], acc[fi][fj]);
    }

    if (EPI == 0) {
        const int which = blockIdx.y / 3;            // N=1152, 384 per which
        u16* dst = (which == 0 ? qo : which == 1 ? ko : vo);
        #pragma unroll
        for (int fi = 0; fi < 4; ++fi) {
            #pragma unroll
            for (int r = 0; r < 4; ++r) {
                const int m = m0 + wm * 64 + fi * 16 + 4 * g + r;
                const int t = m & 511, bb = m >> 9;
                const float csn = cst[t], sn = snt[t];
                #pragma unroll
                for (int fj = 0; fj < 4; ++fj) {
                    const int n = n0 + wn * 64 + fj * 16 + c;
                    float v = acc[fi][fj][r] + bias[n];
                    const float vp = __shfl_xor(v, 1);
                    float ov;
                    if (which < 2)
                        ov = ((n & 1) == 0) ? csn * v - sn * vp : sn * vp + csn * v;
                    else
                        ov = v;
                    const float op = __shfl_xor(ov, 1);
                    if ((c & 1) == 0) {
                        const int rest = n - which * 384;
                        const int h = rest >> 6, d = rest & 63;   // d even
                        const u32 pk = (u32)f2bf(ov) | ((u32)f2bf(op) << 16);
                        *(u32*)&dst[(((size_t)bb * H_ + h) * T_ + t) * 64 + d] = pk;
                    }
                }
            }
        }
    } else {
        #pragma unroll
        for (int fi = 0; fi < 4; ++fi) {
            #pragma unroll
            for (int r = 0; r < 4; ++r) {
                const int m = m0 + wm * 64 + fi * 16 + 4 * g + r;
                #pragma unroll
                for (int fj = 0; fj < 4; ++fj) {
                    const int n = n0 + wn * 64 + fj * 16 + c;
                    float v = fmaxf(acc[fi][fj][r] + bias[n], 0.0f);
                    const float vn = __shfl_xor(v, 1);
                    if ((c & 1) == 0) {
                        const u32 pk = (u32)f2bf(v) | ((u32)f2bf(vn) << 16);
                        *(u32*)&outb[(size_t)m * N + n] = pk;
                    }
                }
            }
        }
    }
}

// ---------------------------------------------------------------------------
// Wide GEMM + bias + residual + LayerNorm, fused.
// Block: 64 rows x 384 cols, 128 threads = 2 waves x (32 rows x 384 cols).
// A [M][KK] bf16, Bt [384][KK] bf16, res fp32 [M][384].
// yf fp32 = LN(acc + bias + res); yb (optional) same in bf16.
// ---------------------------------------------------------------------------
template<int KK>
__global__ __launch_bounds__(128, 2)
void gemm_ln(const u16* __restrict__ A, const u16* __restrict__ Bt,
             const float* __restrict__ bias, const float* __restrict__ res,
             const float* __restrict__ lng, const float* __restrict__ lnb,
             float* __restrict__ yf, u16* __restrict__ yb)
{
    __shared__ u16 As[64 * 32];
    __shared__ u16 Bs[384 * 32];
    const int tid = threadIdx.x;
    const int w = tid >> 6, lane = tid & 63;
    const int c = lane & 15, g = lane >> 4;
    const int cs = (c >> 1) & 3;
    const int m0 = blockIdx.x * 64;
    const int sr = tid >> 2, sch = tid & 3;

    f32x4 acc0[24], acc1[24];
    #pragma unroll
    for (int fn = 0; fn < 24; ++fn) { acc0[fn] = (f32x4)0.0f; acc1[fn] = (f32x4)0.0f; }

    #pragma unroll 2
    for (int k0 = 0; k0 < KK; k0 += 32) {
        __syncthreads();
        #pragma unroll
        for (int i = 0; i < 2; ++i) {
            const int row = sr + i * 32;
            gload16(A + (size_t)(m0 + row) * KK + k0 + swz4(row, sch) * 8,
                    As + (size_t)(i * 128 + w * 64) * 8);
        }
        #pragma unroll
        for (int i = 0; i < 12; ++i) {
            const int row = sr + i * 32;
            gload16(Bt + (size_t)row * KK + k0 + swz4(row, sch) * 8,
                    Bs + (size_t)(i * 128 + w * 64) * 8);
        }
        __syncthreads();
        const bf16x8 a0 = *(const bf16x8*)&As[(w * 32 + c) * 32 + (g ^ cs) * 8];
        const bf16x8 a1 = *(const bf16x8*)&As[(w * 32 + 16 + c) * 32 + (g ^ cs) * 8];
        #pragma unroll
        for (int fn = 0; fn < 24; ++fn) {
            const bf16x8 bfr = *(const bf16x8*)&Bs[(fn * 16 + c) * 32 + (g ^ cs) * 8];
            acc0[fn] = MFMA_BF16(a0, bfr, acc0[fn]);
            acc1[fn] = MFMA_BF16(a1, bfr, acc1[fn]);
        }
    }

    // epilogue: per-row LayerNorm; row = m0 + w*32 + mi*16 + 4g + r
    #pragma unroll
    for (int mi = 0; mi < 2; ++mi) {
        #pragma unroll
        for (int r = 0; r < 4; ++r) {
            const int row = m0 + w * 32 + mi * 16 + 4 * g + r;
            float vals[24];
            float s = 0.0f, s2 = 0.0f;
            #pragma unroll
            for (int fn = 0; fn < 24; ++fn) {
                const int col = fn * 16 + c;
                float v = (mi ? acc1[fn][r] : acc0[fn][r]) + bias[col]
                          + res[(size_t)row * 384 + col];
                vals[fn] = v; s += v; s2 += v * v;
            }
            #pragma unroll
            for (int off = 1; off < 16; off <<= 1) {
                s  += __shfl_xor(s, off);
                s2 += __shfl_xor(s2, off);
            }
            const float mean = s * (1.0f / 384.0f);
            const float var  = s2 * (1.0f / 384.0f) - mean * mean;
            const float inv  = rsqrtf(var + 1e-5f);
            #pragma unroll
            for (int fn = 0; fn < 24; ++fn) {
                const int col = fn * 16 + c;
                const float y = lng[col] * (vals[fn] - mean) * inv + lnb[col];
                yf[(size_t)row * 384 + col] = y;
                if (yb) yb[(size_t)row * 384 + col] = f2bf(y);
            }
        }
    }
}

// ---------------------------------------------------------------------------
// Flash attention, bf16 MFMA.  Block = (qtile, h, b); 4 waves x 16 q-rows.
// ---------------------------------------------------------------------------
#define KS_B(r, chB) ((r) * 176 + (chB) * 16)
#define VT_B(d, t)   ((d) * 176 + ((((t) >> 3) ^ ((d) & 7) ^ ((d) >> 3)) << 4) + (((t) & 7) << 1))

__global__ __launch_bounds__(256)
void attn_mfma(const u16* __restrict__ Q, const u16* __restrict__ K,
               const u16* __restrict__ V, u16* __restrict__ out)
{
    __shared__ u16 Ks[64 * 88];
    __shared__ u16 Vt[64 * 88];
    __shared__ u16 Ps[4][16 * 88];

    const int qt = blockIdx.x, h = blockIdx.y, b = blockIdx.z;
    const int tid = threadIdx.x;
    const int w = tid >> 6, lane = tid & 63;
    const int c = lane & 15, g = lane >> 4;
    const size_t base = ((size_t)b * H_ + h) * T_ * 64;
    const int qrow0 = qt * 64 + w * 16;
    const float scale = 0.05103103630798288f;   // 384^-0.5

    bf16x8 qf[2];
    #pragma unroll
    for (int kh = 0; kh < 2; ++kh)
        qf[kh] = *(const bf16x8*)&Q[base + (size_t)(qrow0 + c) * 64 + kh * 32 + g * 8];

    f32x4 O[4];
    float m_[4], l_[4];
    #pragma unroll
    for (int i = 0; i < 4; ++i) { O[i] = (f32x4)0.0f; m_[i] = -INFINITY; l_[i] = 0.0f; }

    u16* Pw = Ps[w];

    for (int kt = 0; kt <= qt; ++kt) {
        __syncthreads();
        #pragma unroll
        for (int s = 0; s < 2; ++s) {
            const int idx = tid + s * 256;
            const int r = idx >> 3, ch = idx & 7;
            const size_t gsrc = base + (size_t)(kt * 64 + r) * 64 + ch * 8;
            short8 kv = *(const short8*)&K[gsrc];
            *(short8*)((char*)Ks + KS_B(r, ch)) = kv;
            short8 vv = *(const short8*)&V[gsrc];
            #pragma unroll
            for (int j = 0; j < 8; ++j)
                *(u16*)((char*)Vt + VT_B(ch * 8 + j, r)) = (u16)vv[j];
        }
        __syncthreads();

        f32x4 S[4];
        #pragma unroll
        for (int fc = 0; fc < 4; ++fc) {
            S[fc] = (f32x4)0.0f;
            #pragma unroll
            for (int kh = 0; kh < 2; ++kh) {
                bf16x8 kf = *(const bf16x8*)((char*)Ks + KS_B(fc * 16 + c, kh * 4 + g));
                S[fc] = MFMA_BF16(qf[kh], kf, S[fc]);
            }
        }

        const bool diag = (kt == qt);
        #pragma unroll
        for (int r = 0; r < 4; ++r) {
            const int qloc = w * 16 + 4 * g + r;
            float mx = -INFINITY;
            #pragma unroll
            for (int fc = 0; fc < 4; ++fc) {
                float sv = S[fc][r] * scale;
                if (diag && (fc * 16 + c > qloc)) sv = -INFINITY;
                S[fc][r] = sv;
                mx = fmaxf(mx, sv);
            }
            #pragma unroll
            for (int off = 1; off < 16; off <<= 1)
                mx = fmaxf(mx, __shfl_xor(mx, off, 16));
            const float mnew = fmaxf(m_[r], mx);
            const float corr = __expf(m_[r] - mnew);
            m_[r] = mnew;
            float su = 0.0f;
            #pragma unroll
            for (int fc = 0; fc < 4; ++fc) {
                const float p = __expf(S[fc][r] - mnew);
                S[fc][r] = p; su += p;
            }
            #pragma unroll
            for (int off = 1; off < 16; off <<= 1)
                su += __shfl_xor(su, off, 16);
            l_[r] = l_[r] * corr + su;
            #pragma unroll
            for (int fd = 0; fd < 4; ++fd) O[fd][r] *= corr;
        }

        #pragma unroll
        for (int fc = 0; fc < 4; ++fc)
            #pragma unroll
            for (int r = 0; r < 4; ++r)
                *(u16*)((char*)Pw + (4 * g + r) * 176 + (fc * 16 + c) * 2) = f2bf(S[fc][r]);

        bf16x8 pa[2];
        #pragma unroll
        for (int kh = 0; kh < 2; ++kh)
            pa[kh] = *(const bf16x8*)((char*)Pw + c * 176 + kh * 64 + g * 16);
        #pragma unroll
        for (int fd = 0; fd < 4; ++fd) {
            const int d = fd * 16 + c;
            #pragma unroll
            for (int kh = 0; kh < 2; ++kh) {
                const int kb = kh * 4 + g;
                bf16x8 vf = *(const bf16x8*)((char*)Vt + d * 176 + (((kb) ^ (d & 7) ^ (d >> 3)) << 4));
                O[fd] = MFMA_BF16(pa[kh], vf, O[fd]);
            }
        }
    }

    #pragma unroll
    for (int r = 0; r < 4; ++r) {
        const int t = qrow0 + 4 * g + r;
        const float inv = 1.0f / l_[r];
        const size_t o = ((size_t)b * T_ + t) * C_ + h * 64;
        #pragma unroll
        for (int fd = 0; fd < 4; ++fd)
            out[o + fd * 16 + c] = f2bf(O[fd][r] * inv);
    }
}

// ---------------------------------------------------------------------------
extern "C" void kernel_launch(void* const* d_in, const int* in_sizes, int n_in,
                              void* d_out, int out_size, void* d_ws, size_t ws_size,
                              hipStream_t stream)
{
    const float* x    = (const float*)d_in[0];
    const float* q1w  = (const float*)d_in[1];  const float* q1b = (const float*)d_in[2];
    const float* k1w  = (const float*)d_in[3];  const float* k1b = (const float*)d_in[4];
    const float* v1w  = (const float*)d_in[5];  const float* v1b = (const float*)d_in[6];
    const float* p1w  = (const float*)d_in[7];  const float* p1b = (const float*)d_in[8];
    const float* ln1g = (const float*)d_in[9];  const float* ln1b = (const float*)d_in[10];
    const float* q2w  = (const float*)d_in[11]; const float* q2b = (const float*)d_in[12];
    const float* k2w  = (const float*)d_in[13]; const float* k2b = (const float*)d_in[14];
    const float* v2w  = (const float*)d_in[15]; const float* v2b = (const float*)d_in[16];
    const float* p2w  = (const float*)d_in[17]; const float* p2b = (const float*)d_in[18];
    const float* ln2g = (const float*)d_in[19]; const float* ln2b = (const float*)d_in[20];
    const float* f1w  = (const float*)d_in[21]; const float* f1b = (const float*)d_in[22];
    const float* f2w  = (const float*)d_in[23]; const float* f2b = (const float*)d_in[24];
    const float* ln3g = (const float*)d_in[25]; const float* ln3b = (const float*)d_in[26];

    // ---- workspace: bf16 weights + fp32 tables + chunk slices ----
    const size_t WQKV = 1152 * 384, WP = 384 * 384, WF = 1536 * 384;
    u16* wq1 = (u16*)d_ws;
    u16* wq2 = wq1 + WQKV;
    u16* p1t = wq2 + WQKV;
    u16* p2t = p1t + WP;
    u16* f1t = p2t + WP;
    u16* f2t = f1t + WF;
    float* bq1 = (float*)(f2t + WF);
    float* bq2 = bq1 + 1152;
    float* cst = bq2 + 1152;
    float* snt = cst + 512;
    u16* chunkBase = (u16*)(snt + 512);
    const size_t fixedBytes = (size_t)((char*)chunkBase - (char*)d_ws);

    int CB = 64;
    while (CB > 1 && fixedBytes + 20ull * CB * T_ * C_ > ws_size) CB >>= 1;
    const size_t McC = (size_t)CB * T_ * C_;
    const int Mc = CB * T_;

    u16* sQ  = chunkBase;
    u16* sK  = sQ + McC;
    u16* sV  = sK + McC;
    u16* sAb = sV + McC;
    u16* sX  = sAb + McC;        // x-cast, then y1 bf16
    u16* sO2 = sX + McC;         // y2 bf16
    u16* tmp = sQ;               // FF intermediate overlays q,k,v,abuf
    float* y1f = (float*)(sO2 + McC);
    float* y2f = y1f + McC;

    const dim3 blk(256);

    prep_kernel<<<dim3(2304, 7), blk, 0, stream>>>(
        q1w, k1w, v1w, q2w, k2w, v2w, p1w, p2w, f1w, f2w,
        q1b, k1b, v1b, q2b, k2b, v2b,
        wq1, wq2, p1t, p2t, f1t, f2t, bq1, bq2, cst, snt);

    for (int b0 = 0; b0 < B_; b0 += CB) {
        const float* xc = x + (size_t)b0 * T_ * C_;
        float*       oc = (float*)d_out + (size_t)b0 * T_ * C_;

        cast_kernel<<<dim3(2048), blk, 0, stream>>>(xc, sX, (int)(McC / 4));

        // ---- layer 1 ----
        gemm_mfma<0><<<dim3(Mc / 128, 9), blk, 0, stream>>>(sX, wq1, 384, bq1,
            nullptr, sQ, sK, sV, cst, snt, 1152);
        attn_mfma<<<dim3(T_ / 64, H_, CB), blk, 0, stream>>>(sQ, sK, sV, sAb);
        gemm_ln<384><<<dim3(Mc / 64), dim3(128), 0, stream>>>(sAb, p1t, p1b, xc,
            ln1g, ln1b, y1f, sX);

        // ---- layer 2 ----
        gemm_mfma<0><<<dim3(Mc / 128, 9), blk, 0, stream>>>(sX, wq2, 384, bq2,
            nullptr, sQ, sK, sV, cst, snt, 1152);
        attn_mfma<<<dim3(T_ / 64, H_, CB), blk, 0, stream>>>(sQ, sK, sV, sAb);
        gemm_ln<384><<<dim3(Mc / 64), dim3(128), 0, stream>>>(sAb, p2t, p2b, y1f,
            ln2g, ln2b, y2f, sO2);

        // ---- feed-forward ----
        gemm_mfma<2><<<dim3(Mc / 128, 12), blk, 0, stream>>>(sO2, f1t, 384, f1b,
            tmp, nullptr, nullptr, nullptr, cst, snt, 1536);
        gemm_ln<1536><<<dim3(Mc / 64), dim3(128), 0, stream>>>(tmp, f2t, f2b, y2f,
            ln3g, ln3b, oc, nullptr);
    }
}

// Round 5
// 814.586 us; speedup vs baseline: 1.0729x; 1.0729x over previous
//
#include <hip/hip_runtime.h>
#include <cstddef>
#include <cstdint>

#define B_ 64
#define T_ 512
#define C_ 384
#define H_ 6
#define HD_ 64
#define FF_ 1536

typedef unsigned short u16;
typedef unsigned int u32;
typedef __attribute__((ext_vector_type(8))) __bf16 bf16x8;
typedef __attribute__((ext_vector_type(8))) short short8;
typedef __attribute__((ext_vector_type(4))) float f32x4;

#define MFMA_BF16(a, b, c) __builtin_amdgcn_mfma_f32_16x16x32_bf16((a), (b), (c), 0, 0, 0)

__device__ __forceinline__ u16 f2bf(float f) {
    union { float f; unsigned u; } x; x.f = f;
    unsigned r = x.u + 0x7fff + ((x.u >> 16) & 1);   // RTNE
    return (u16)(r >> 16);
}

__device__ __forceinline__ void gload16(const u16* g, u16* l) {
    __builtin_amdgcn_global_load_lds(
        (const __attribute__((address_space(1))) void*)g,
        (__attribute__((address_space(3))) void*)l, 16, 0, 0);
}

// chunk swizzle for 64B-row LDS tiles (32 bf16/row, 4x16B chunks):
// LDS[row][ch] holds global[row][ch ^ ((row>>1)&3)] -> reads spread over 8 bank-slots
__device__ __forceinline__ int swz4(int row, int ch) { return ch ^ ((row >> 1) & 3); }

// ---------------------------------------------------------------------------
// prep: cast + transpose weights to bf16 [N][K], concat qkv biases, trig table
// ---------------------------------------------------------------------------
__global__ __launch_bounds__(256)
void prep_kernel(const float* __restrict__ q1w, const float* __restrict__ k1w, const float* __restrict__ v1w,
                 const float* __restrict__ q2w, const float* __restrict__ k2w, const float* __restrict__ v2w,
                 const float* __restrict__ p1w, const float* __restrict__ p2w,
                 const float* __restrict__ f1w, const float* __restrict__ f2w,
                 const float* __restrict__ q1b, const float* __restrict__ k1b, const float* __restrict__ v1b,
                 const float* __restrict__ q2b, const float* __restrict__ k2b, const float* __restrict__ v2b,
                 u16* wq1, u16* wq2, u16* p1t, u16* p2t, u16* f1t, u16* f2t,
                 float* bq1, float* bq2, float* cst, float* snt)
{
    const int job = blockIdx.y;
    const int idx = blockIdx.x * 256 + threadIdx.x;
    if (job <= 1) {                       // qkv: [n=1152][k=384], n = which*384+h*64+d
        if (idx >= 1152 * 384) return;
        const int n = idx / 384, k = idx - n * 384;
        const int wsel = n / 384;
        const int rest = n - wsel * 384;
        const int h = rest >> 6, d = rest & 63;
        const float* src;
        if (job == 0) src = (wsel == 0 ? q1w : wsel == 1 ? k1w : v1w);
        else          src = (wsel == 0 ? q2w : wsel == 1 ? k2w : v2w);
        (job == 0 ? wq1 : wq2)[idx] = f2bf(src[((size_t)h * 384 + k) * 64 + d]);
    } else if (job <= 3) {                // proj: [n=384][k=384] = pw[k][n]
        if (idx >= 384 * 384) return;
        const int n = idx / 384, k = idx - n * 384;
        const float* src = (job == 2 ? p1w : p2w);
        (job == 2 ? p1t : p2t)[idx] = f2bf(src[(size_t)k * 384 + n]);
    } else if (job == 4) {                // f1: [n=1536][k=384]
        if (idx >= 1536 * 384) return;
        const int n = idx / 384, k = idx - n * 384;
        f1t[idx] = f2bf(f1w[(size_t)k * 1536 + n]);
    } else if (job == 5) {                // f2: [n=384][k=1536]
        if (idx >= 384 * 1536) return;
        const int n = idx / 1536, k = idx - n * 1536;
        f2t[idx] = f2bf(f2w[(size_t)k * 384 + n]);
    } else {
        if (idx < 1152) {
            const int wsel = idx / 384, r = idx - wsel * 384;
            bq1[idx] = (wsel == 0 ? q1b : wsel == 1 ? k1b : v1b)[r];
        } else if (idx < 2304) {
            const int j = idx - 1152;
            const int wsel = j / 384, r = j - wsel * 384;
            bq2[j] = (wsel == 0 ? q2b : wsel == 1 ? k2b : v2b)[r];
        } else if (idx < 2816) {
            const int t = idx - 2304; cst[t] = cosf((float)t);
        } else if (idx < 3328) {
            const int t = idx - 2816; snt[t] = sinf((float)t);
        }
    }
}

// ---------------------------------------------------------------------------
__global__ __launch_bounds__(256)
void cast_kernel(const float* __restrict__ in, u16* __restrict__ out, int n4)
{
    int i = blockIdx.x * 256 + threadIdx.x;
    const int stride = gridDim.x * 256;
    for (; i < n4; i += stride) {
        float4 v = *reinterpret_cast<const float4*>(&in[(size_t)i * 4]);
        ushort4 o;
        o.x = f2bf(v.x); o.y = f2bf(v.y); o.z = f2bf(v.z); o.w = f2bf(v.w);
        *reinterpret_cast<ushort4*>(&out[(size_t)i * 4]) = o;
    }
}

// ---------------------------------------------------------------------------
// bf16 MFMA GEMM, tile 128x128, BK=32, 4 waves (2x2), 4x4 frags/wave.
// 2-phase double-buffered LDS: prefetch K-step t+1 while computing t, so the
// global_load_lds latency hides under ds_read+MFMA (we run at low occupancy;
// wave-level overlap alone can't cover the vmcnt(0) drain).
// A [M][K], Bt [N][K] bf16.  Swizzled staging (conflict-free ds_read_b128).
// EPI 0: QKV (bias + RoPE for q,k; scatter to q/k/v [b,h,t,d] bf16)
// EPI 1: outf = acc + bias[n] + res[m][n]   (fp32)
// EPI 2: outb = relu(acc + bias[n])         (bf16, paired u32 stores)
// ---------------------------------------------------------------------------
template<int EPI>
__global__ __launch_bounds__(256)
void gemm_mfma(const u16* __restrict__ A, const u16* __restrict__ Bt, int K,
               const float* __restrict__ bias, const float* __restrict__ res,
               float* __restrict__ outf, u16* __restrict__ outb,
               u16* __restrict__ qo, u16* __restrict__ ko, u16* __restrict__ vo,
               const float* __restrict__ cst, const float* __restrict__ snt,
               int N)
{
    __shared__ u16 As[2][128 * 32];
    __shared__ u16 Bs[2][128 * 32];
    const int tid = threadIdx.x;
    const int w = tid >> 6, lane = tid & 63;
    const int m0 = blockIdx.x * 128, n0 = blockIdx.y * 128;
    const int wm = w >> 1, wn = w & 1;
    const int c = lane & 15, g = lane >> 4;
    const int cs = (c >> 1) & 3;

    const int srow = w * 16 + (lane >> 2);            // 0..63
    const u16* gA = A + (size_t)(m0 + srow) * K + swz4(srow, lane & 3) * 8;
    const u16* gB = Bt + (size_t)(n0 + srow) * K + swz4(srow, lane & 3) * 8;
    const int ldst = w * 512;                          // per-wave LDS dest offset

    f32x4 acc[4][4];
    #pragma unroll
    for (int i = 0; i < 4; ++i)
        #pragma unroll
        for (int j = 0; j < 4; ++j) acc[i][j] = (f32x4)0.0f;

    const int NT = K >> 5;

    // prologue: stage tile 0
    gload16(gA, As[0] + ldst);
    gload16(gA + (size_t)64 * K, As[0] + 64 * 32 + ldst);
    gload16(gB, Bs[0] + ldst);
    gload16(gB + (size_t)64 * K, Bs[0] + 64 * 32 + ldst);
    __syncthreads();                                   // drains vmcnt(0)

    for (int t = 0; t < NT; ++t) {
        const int cur = t & 1;
        if (t + 1 < NT) {                              // prefetch next tile
            const int k0 = (t + 1) * 32;
            gload16(gA + k0, As[cur ^ 1] + ldst);
            gload16(gA + k0 + (size_t)64 * K, As[cur ^ 1] + 64 * 32 + ldst);
            gload16(gB + k0, Bs[cur ^ 1] + ldst);
            gload16(gB + k0 + (size_t)64 * K, Bs[cur ^ 1] + 64 * 32 + ldst);
        }
        bf16x8 af[4], bfr[4];
        #pragma unroll
        for (int fi = 0; fi < 4; ++fi)
            af[fi] = *(const bf16x8*)&As[cur][(wm * 64 + fi * 16 + c) * 32 + (g ^ cs) * 8];
        #pragma unroll
        for (int fj = 0; fj < 4; ++fj)
            bfr[fj] = *(const bf16x8*)&Bs[cur][(wn * 64 + fj * 16 + c) * 32 + (g ^ cs) * 8];
        #pragma unroll
        for (int fi = 0; fi < 4; ++fi)
            #pragma unroll
            for (int fj = 0; fj < 4; ++fj)
                acc[fi][fj] = MFMA_BF16(af[fi], bfr[fj], acc[fi][fj]);
        __syncthreads();   // drains vmcnt(0) (prefetch landed) + read-safety
    }

    if (EPI == 0) {
        const int which = blockIdx.y / 3;            // N=1152, 384 per which
        u16* dst = (which == 0 ? qo : which == 1 ? ko : vo);
        #pragma unroll
        for (int fi = 0; fi < 4; ++fi) {
            #pragma unroll
            for (int r = 0; r < 4; ++r) {
                const int m = m0 + wm * 64 + fi * 16 + 4 * g + r;
                const int t = m & 511, bb = m >> 9;
                const float csn = cst[t], sn = snt[t];
                #pragma unroll
                for (int fj = 0; fj < 4; ++fj) {
                    const int n = n0 + wn * 64 + fj * 16 + c;
                    float v = acc[fi][fj][r] + bias[n];
                    const float vp = __shfl_xor(v, 1);
                    float ov;
                    if (which < 2)
                        ov = ((n & 1) == 0) ? csn * v - sn * vp : sn * vp + csn * v;
                    else
                        ov = v;
                    const float op = __shfl_xor(ov, 1);
                    if ((c & 1) == 0) {
                        const int rest = n - which * 384;
                        const int h = rest >> 6, d = rest & 63;   // d even
                        const u32 pk = (u32)f2bf(ov) | ((u32)f2bf(op) << 16);
                        *(u32*)&dst[(((size_t)bb * H_ + h) * T_ + t) * 64 + d] = pk;
                    }
                }
            }
        }
    } else if (EPI == 1) {
        #pragma unroll
        for (int fi = 0; fi < 4; ++fi) {
            #pragma unroll
            for (int r = 0; r < 4; ++r) {
                const int m = m0 + wm * 64 + fi * 16 + 4 * g + r;
                #pragma unroll
                for (int fj = 0; fj < 4; ++fj) {
                    const int n = n0 + wn * 64 + fj * 16 + c;
                    float v = acc[fi][fj][r] + bias[n] + res[(size_t)m * N + n];
                    outf[(size_t)m * N + n] = v;
                }
            }
        }
    } else {
        #pragma unroll
        for (int fi = 0; fi < 4; ++fi) {
            #pragma unroll
            for (int r = 0; r < 4; ++r) {
                const int m = m0 + wm * 64 + fi * 16 + 4 * g + r;
                #pragma unroll
                for (int fj = 0; fj < 4; ++fj) {
                    const int n = n0 + wn * 64 + fj * 16 + c;
                    float v = fmaxf(acc[fi][fj][r] + bias[n], 0.0f);
                    const float vn = __shfl_xor(v, 1);
                    if ((c & 1) == 0) {
                        const u32 pk = (u32)f2bf(v) | ((u32)f2bf(vn) << 16);
                        *(u32*)&outb[(size_t)m * N + n] = pk;
                    }
                }
            }
        }
    }
}

// ---------------------------------------------------------------------------
// Flash attention, bf16 MFMA.  Block = (qtile, h, b); 4 waves x 16 q-rows.
// ---------------------------------------------------------------------------
#define KS_B(r, chB) ((r) * 176 + (chB) * 16)
#define VT_B(d, t)   ((d) * 176 + ((((t) >> 3) ^ ((d) & 7) ^ ((d) >> 3)) << 4) + (((t) & 7) << 1))

__global__ __launch_bounds__(256)
void attn_mfma(const u16* __restrict__ Q, const u16* __restrict__ K,
               const u16* __restrict__ V, u16* __restrict__ out)
{
    __shared__ u16 Ks[64 * 88];
    __shared__ u16 Vt[64 * 88];
    __shared__ u16 Ps[4][16 * 88];

    const int qt = blockIdx.x, h = blockIdx.y, b = blockIdx.z;
    const int tid = threadIdx.x;
    const int w = tid >> 6, lane = tid & 63;
    const int c = lane & 15, g = lane >> 4;
    const size_t base = ((size_t)b * H_ + h) * T_ * 64;
    const int qrow0 = qt * 64 + w * 16;
    const float scale = 0.05103103630798288f;   // 384^-0.5

    bf16x8 qf[2];
    #pragma unroll
    for (int kh = 0; kh < 2; ++kh)
        qf[kh] = *(const bf16x8*)&Q[base + (size_t)(qrow0 + c) * 64 + kh * 32 + g * 8];

    f32x4 O[4];
    float m_[4], l_[4];
    #pragma unroll
    for (int i = 0; i < 4; ++i) { O[i] = (f32x4)0.0f; m_[i] = -INFINITY; l_[i] = 0.0f; }

    u16* Pw = Ps[w];

    for (int kt = 0; kt <= qt; ++kt) {
        __syncthreads();
        #pragma unroll
        for (int s = 0; s < 2; ++s) {
            const int idx = tid + s * 256;
            const int r = idx >> 3, ch = idx & 7;
            const size_t gsrc = base + (size_t)(kt * 64 + r) * 64 + ch * 8;
            short8 kv = *(const short8*)&K[gsrc];
            *(short8*)((char*)Ks + KS_B(r, ch)) = kv;
            short8 vv = *(const short8*)&V[gsrc];
            #pragma unroll
            for (int j = 0; j < 8; ++j)
                *(u16*)((char*)Vt + VT_B(ch * 8 + j, r)) = (u16)vv[j];
        }
        __syncthreads();

        f32x4 S[4];
        #pragma unroll
        for (int fc = 0; fc < 4; ++fc) {
            S[fc] = (f32x4)0.0f;
            #pragma unroll
            for (int kh = 0; kh < 2; ++kh) {
                bf16x8 kf = *(const bf16x8*)((char*)Ks + KS_B(fc * 16 + c, kh * 4 + g));
                S[fc] = MFMA_BF16(qf[kh], kf, S[fc]);
            }
        }

        const bool diag = (kt == qt);
        #pragma unroll
        for (int r = 0; r < 4; ++r) {
            const int qloc = w * 16 + 4 * g + r;
            float mx = -INFINITY;
            #pragma unroll
            for (int fc = 0; fc < 4; ++fc) {
                float sv = S[fc][r] * scale;
                if (diag && (fc * 16 + c > qloc)) sv = -INFINITY;
                S[fc][r] = sv;
                mx = fmaxf(mx, sv);
            }
            #pragma unroll
            for (int off = 1; off < 16; off <<= 1)
                mx = fmaxf(mx, __shfl_xor(mx, off, 16));
            const float mnew = fmaxf(m_[r], mx);
            const float corr = __expf(m_[r] - mnew);
            m_[r] = mnew;
            float su = 0.0f;
            #pragma unroll
            for (int fc = 0; fc < 4; ++fc) {
                const float p = __expf(S[fc][r] - mnew);
                S[fc][r] = p; su += p;
            }
            #pragma unroll
            for (int off = 1; off < 16; off <<= 1)
                su += __shfl_xor(su, off, 16);
            l_[r] = l_[r] * corr + su;
            #pragma unroll
            for (int fd = 0; fd < 4; ++fd) O[fd][r] *= corr;
        }

        #pragma unroll
        for (int fc = 0; fc < 4; ++fc)
            #pragma unroll
            for (int r = 0; r < 4; ++r)
                *(u16*)((char*)Pw + (4 * g + r) * 176 + (fc * 16 + c) * 2) = f2bf(S[fc][r]);

        bf16x8 pa[2];
        #pragma unroll
        for (int kh = 0; kh < 2; ++kh)
            pa[kh] = *(const bf16x8*)((char*)Pw + c * 176 + kh * 64 + g * 16);
        #pragma unroll
        for (int fd = 0; fd < 4; ++fd) {
            const int d = fd * 16 + c;
            #pragma unroll
            for (int kh = 0; kh < 2; ++kh) {
                const int kb = kh * 4 + g;
                bf16x8 vf = *(const bf16x8*)((char*)Vt + d * 176 + (((kb) ^ (d & 7) ^ (d >> 3)) << 4));
                O[fd] = MFMA_BF16(pa[kh], vf, O[fd]);
            }
        }
    }

    #pragma unroll
    for (int r = 0; r < 4; ++r) {
        const int t = qrow0 + 4 * g + r;
        const float inv = 1.0f / l_[r];
        const size_t o = ((size_t)b * T_ + t) * C_ + h * 64;
        #pragma unroll
        for (int fd = 0; fd < 4; ++fd)
            out[o + fd * 16 + c] = f2bf(O[fd][r] * inv);
    }
}

// ---------------------------------------------------------------------------
// LayerNorm over C=384, fp32 in, fp32 and/or bf16 out.  1 wave/row.
// ---------------------------------------------------------------------------
__global__ __launch_bounds__(256)
void ln_kernel(const float* __restrict__ in, const float* __restrict__ gam,
               const float* __restrict__ bta, float* __restrict__ outf,
               u16* __restrict__ outb)
{
    const int lane = threadIdx.x & 63;
    const int wv   = threadIdx.x >> 6;
    const size_t row = (size_t)blockIdx.x * 4 + wv;
    const float* x = in + row * C_;

    float vals[6];
    float s = 0.0f;
    #pragma unroll
    for (int i = 0; i < 6; ++i) { vals[i] = x[lane + i * 64]; s += vals[i]; }
    #pragma unroll
    for (int off = 1; off < 64; off <<= 1) s += __shfl_xor(s, off, 64);
    const float mean = s * (1.0f / 384.0f);

    float vs = 0.0f;
    #pragma unroll
    for (int i = 0; i < 6; ++i) { const float d = vals[i] - mean; vs += d * d; }
    #pragma unroll
    for (int off = 1; off < 64; off <<= 1) vs += __shfl_xor(vs, off, 64);
    const float inv = rsqrtf(vs * (1.0f / 384.0f) + 1e-5f);

    #pragma unroll
    for (int i = 0; i < 6; ++i) {
        const int cc = lane + i * 64;
        const float y = gam[cc] * (vals[i] - mean) * inv + bta[cc];
        if (outf) outf[row * C_ + cc] = y;
        if (outb) outb[row * C_ + cc] = f2bf(y);
    }
}

// ---------------------------------------------------------------------------
extern "C" void kernel_launch(void* const* d_in, const int* in_sizes, int n_in,
                              void* d_out, int out_size, void* d_ws, size_t ws_size,
                              hipStream_t stream)
{
    const float* x    = (const float*)d_in[0];
    const float* q1w  = (const float*)d_in[1];  const float* q1b = (const float*)d_in[2];
    const float* k1w  = (const float*)d_in[3];  const float* k1b = (const float*)d_in[4];
    const float* v1w  = (const float*)d_in[5];  const float* v1b = (const float*)d_in[6];
    const float* p1w  = (const float*)d_in[7];  const float* p1b = (const float*)d_in[8];
    const float* ln1g = (const float*)d_in[9];  const float* ln1b = (const float*)d_in[10];
    const float* q2w  = (const float*)d_in[11]; const float* q2b = (const float*)d_in[12];
    const float* k2w  = (const float*)d_in[13]; const float* k2b = (const float*)d_in[14];
    const float* v2w  = (const float*)d_in[15]; const float* v2b = (const float*)d_in[16];
    const float* p2w  = (const float*)d_in[17]; const float* p2b = (const float*)d_in[18];
    const float* ln2g = (const float*)d_in[19]; const float* ln2b = (const float*)d_in[20];
    const float* f1w  = (const float*)d_in[21]; const float* f1b = (const float*)d_in[22];
    const float* f2w  = (const float*)d_in[23]; const float* f2b = (const float*)d_in[24];
    const float* ln3g = (const float*)d_in[25]; const float* ln3b = (const float*)d_in[26];

    // ---- workspace: bf16 weights + fp32 tables + chunk slices ----
    const size_t WQKV = 1152 * 384, WP = 384 * 384, WF = 1536 * 384;
    u16* wq1 = (u16*)d_ws;
    u16* wq2 = wq1 + WQKV;
    u16* p1t = wq2 + WQKV;
    u16* p2t = p1t + WP;
    u16* f1t = p2t + WP;
    u16* f2t = f1t + WF;
    float* bq1 = (float*)(f2t + WF);
    float* bq2 = bq1 + 1152;
    float* cst = bq2 + 1152;
    float* snt = cst + 512;
    u16* chunkBase = (u16*)(snt + 512);
    const size_t fixedBytes = (size_t)((char*)chunkBase - (char*)d_ws);

    // 6 bf16 slices + 2 fp32 slices of Mc*C each = 20 B per element
    int CB = 64;
    while (CB > 1 && fixedBytes + 20ull * CB * T_ * C_ > ws_size) CB >>= 1;
    const size_t McC = (size_t)CB * T_ * C_;
    const int Mc = CB * T_;

    u16* sQ  = chunkBase;
    u16* sK  = sQ + McC;
    u16* sV  = sK + McC;
    u16* sAb = sV + McC;
    u16* sX  = sAb + McC;        // x-cast, then y1 bf16
    u16* sO2 = sX + McC;         // y2 bf16
    u16* tmp = sQ;               // FF intermediate overlays q,k,v,abuf
    float* bufF = (float*)(sO2 + McC);
    float* y1f  = bufF + McC;

    const dim3 blk(256);

    prep_kernel<<<dim3(2304, 7), blk, 0, stream>>>(
        q1w, k1w, v1w, q2w, k2w, v2w, p1w, p2w, f1w, f2w,
        q1b, k1b, v1b, q2b, k2b, v2b,
        wq1, wq2, p1t, p2t, f1t, f2t, bq1, bq2, cst, snt);

    for (int b0 = 0; b0 < B_; b0 += CB) {
        const float* xc = x + (size_t)b0 * T_ * C_;
        float*       oc = (float*)d_out + (size_t)b0 * T_ * C_;

        cast_kernel<<<dim3(2048), blk, 0, stream>>>(xc, sX, (int)(McC / 4));

        // ---- layer 1 ----
        gemm_mfma<0><<<dim3(Mc / 128, 9), blk, 0, stream>>>(sX, wq1, 384, bq1,
            nullptr, nullptr, nullptr, sQ, sK, sV, cst, snt, 1152);
        attn_mfma<<<dim3(T_ / 64, H_, CB), blk, 0, stream>>>(sQ, sK, sV, sAb);
        gemm_mfma<1><<<dim3(Mc / 128, 3), blk, 0, stream>>>(sAb, p1t, 384, p1b,
            xc, bufF, nullptr, nullptr, nullptr, nullptr, cst, snt, 384);
        ln_kernel<<<dim3(Mc / 4), blk, 0, stream>>>(bufF, ln1g, ln1b, y1f, sX);

        // ---- layer 2 ----
        gemm_mfma<0><<<dim3(Mc / 128, 9), blk, 0, stream>>>(sX, wq2, 384, bq2,
            nullptr, nullptr, nullptr, sQ, sK, sV, cst, snt, 1152);
        attn_mfma<<<dim3(T_ / 64, H_, CB), blk, 0, stream>>>(sQ, sK, sV, sAb);
        gemm_mfma<1><<<dim3(Mc / 128, 3), blk, 0, stream>>>(sAb, p2t, 384, p2b,
            y1f, bufF, nullptr, nullptr, nullptr, nullptr, cst, snt, 384);
        ln_kernel<<<dim3(Mc / 4), blk, 0, stream>>>(bufF, ln2g, ln2b, oc, sO2);

        // ---- feed-forward ----
        gemm_mfma<2><<<dim3(Mc / 128, 12), blk, 0, stream>>>(sO2, f1t, 384, f1b,
            nullptr, nullptr, tmp, nullptr, nullptr, nullptr, cst, snt, 1536);
        gemm_mfma<1><<<dim3(Mc / 128, 3), blk, 0, stream>>>(tmp, f2t, 1536, f2b,
            oc, bufF, nullptr, nullptr, nullptr, nullptr, cst, snt, 384);
        ln_kernel<<<dim3(Mc / 4), blk, 0, stream>>>(bufF, ln3g, ln3b, oc, nullptr);
    }
}

// Round 6
// 803.169 us; speedup vs baseline: 1.0881x; 1.0142x over previous
//
#include <hip/hip_runtime.h>
#include <cstddef>
#include <cstdint>

#define B_ 64
#define T_ 512
#define C_ 384
#define H_ 6
#define HD_ 64
#define FF_ 1536

typedef unsigned short u16;
typedef unsigned int u32;
typedef __attribute__((ext_vector_type(8))) __bf16 bf16x8;
typedef __attribute__((ext_vector_type(8))) short short8;
typedef __attribute__((ext_vector_type(4))) float f32x4;

#define MFMA_BF16(a, b, c) __builtin_amdgcn_mfma_f32_16x16x32_bf16((a), (b), (c), 0, 0, 0)

__device__ __forceinline__ u16 f2bf(float f) {
    union { float f; unsigned u; } x; x.f = f;
    unsigned r = x.u + 0x7fff + ((x.u >> 16) & 1);   // RTNE
    return (u16)(r >> 16);
}

__device__ __forceinline__ void gload16(const u16* g, u16* l) {
    __builtin_amdgcn_global_load_lds(
        (const __attribute__((address_space(1))) void*)g,
        (__attribute__((address_space(3))) void*)l, 16, 0, 0);
}

// chunk swizzle for 64B-row LDS tiles (32 bf16/row, 4x16B chunks):
// LDS[row][ch] holds global[row][ch ^ ((row>>1)&3)] -> reads spread over 8 bank-slots
__device__ __forceinline__ int swz4(int row, int ch) { return ch ^ ((row >> 1) & 3); }

// ---------------------------------------------------------------------------
// prep: cast + transpose weights to bf16 [N][K], concat qkv biases, trig table
// ---------------------------------------------------------------------------
__global__ __launch_bounds__(256)
void prep_kernel(const float* __restrict__ q1w, const float* __restrict__ k1w, const float* __restrict__ v1w,
                 const float* __restrict__ q2w, const float* __restrict__ k2w, const float* __restrict__ v2w,
                 const float* __restrict__ p1w, const float* __restrict__ p2w,
                 const float* __restrict__ f1w, const float* __restrict__ f2w,
                 const float* __restrict__ q1b, const float* __restrict__ k1b, const float* __restrict__ v1b,
                 const float* __restrict__ q2b, const float* __restrict__ k2b, const float* __restrict__ v2b,
                 u16* wq1, u16* wq2, u16* p1t, u16* p2t, u16* f1t, u16* f2t,
                 float* bq1, float* bq2, float* cst, float* snt)
{
    const int job = blockIdx.y;
    const int idx = blockIdx.x * 256 + threadIdx.x;
    if (job <= 1) {                       // qkv: [n=1152][k=384], n = which*384+h*64+d
        if (idx >= 1152 * 384) return;
        const int n = idx / 384, k = idx - n * 384;
        const int wsel = n / 384;
        const int rest = n - wsel * 384;
        const int h = rest >> 6, d = rest & 63;
        const float* src;
        if (job == 0) src = (wsel == 0 ? q1w : wsel == 1 ? k1w : v1w);
        else          src = (wsel == 0 ? q2w : wsel == 1 ? k2w : v2w);
        (job == 0 ? wq1 : wq2)[idx] = f2bf(src[((size_t)h * 384 + k) * 64 + d]);
    } else if (job <= 3) {                // proj: [n=384][k=384] = pw[k][n]
        if (idx >= 384 * 384) return;
        const int n = idx / 384, k = idx - n * 384;
        const float* src = (job == 2 ? p1w : p2w);
        (job == 2 ? p1t : p2t)[idx] = f2bf(src[(size_t)k * 384 + n]);
    } else if (job == 4) {                // f1: [n=1536][k=384]
        if (idx >= 1536 * 384) return;
        const int n = idx / 384, k = idx - n * 384;
        f1t[idx] = f2bf(f1w[(size_t)k * 1536 + n]);
    } else if (job == 5) {                // f2: [n=384][k=1536]
        if (idx >= 384 * 1536) return;
        const int n = idx / 1536, k = idx - n * 1536;
        f2t[idx] = f2bf(f2w[(size_t)k * 384 + n]);
    } else {
        if (idx < 1152) {
            const int wsel = idx / 384, r = idx - wsel * 384;
            bq1[idx] = (wsel == 0 ? q1b : wsel == 1 ? k1b : v1b)[r];
        } else if (idx < 2304) {
            const int j = idx - 1152;
            const int wsel = j / 384, r = j - wsel * 384;
            bq2[j] = (wsel == 0 ? q2b : wsel == 1 ? k2b : v2b)[r];
        } else if (idx < 2816) {
            const int t = idx - 2304; cst[t] = cosf((float)t);
        } else if (idx < 3328) {
            const int t = idx - 2816; snt[t] = sinf((float)t);
        }
    }
}

// ---------------------------------------------------------------------------
__global__ __launch_bounds__(256)
void cast_kernel(const float* __restrict__ in, u16* __restrict__ out, int n4)
{
    int i = blockIdx.x * 256 + threadIdx.x;
    const int stride = gridDim.x * 256;
    for (; i < n4; i += stride) {
        float4 v = *reinterpret_cast<const float4*>(&in[(size_t)i * 4]);
        ushort4 o;
        o.x = f2bf(v.x); o.y = f2bf(v.y); o.z = f2bf(v.z); o.w = f2bf(v.w);
        *reinterpret_cast<ushort4*>(&out[(size_t)i * 4]) = o;
    }
}

// ---------------------------------------------------------------------------
// bf16 MFMA GEMM, tile 128x128, BK=32, 4 waves (2x2), 4x4 frags/wave.
// 2-phase double-buffered LDS (prefetch K-step t+1 while computing t).
// EPI 0: QKV (bias + RoPE for q,k; scatter to q/k/v [b,h,t,d] bf16)
// EPI 1: outf = acc + bias[n] + res[m][n]   (fp32)
// EPI 2: outb = relu(acc + bias[n])         (bf16, paired u32 stores)
// ---------------------------------------------------------------------------
template<int EPI>
__global__ __launch_bounds__(256)
void gemm_mfma(const u16* __restrict__ A, const u16* __restrict__ Bt, int K,
               const float* __restrict__ bias, const float* __restrict__ res,
               float* __restrict__ outf, u16* __restrict__ outb,
               u16* __restrict__ qo, u16* __restrict__ ko, u16* __restrict__ vo,
               const float* __restrict__ cst, const float* __restrict__ snt,
               int N)
{
    __shared__ u16 As[2][128 * 32];
    __shared__ u16 Bs[2][128 * 32];
    const int tid = threadIdx.x;
    const int w = tid >> 6, lane = tid & 63;
    const int m0 = blockIdx.x * 128, n0 = blockIdx.y * 128;
    const int wm = w >> 1, wn = w & 1;
    const int c = lane & 15, g = lane >> 4;
    const int cs = (c >> 1) & 3;

    const int srow = w * 16 + (lane >> 2);            // 0..63
    const u16* gA = A + (size_t)(m0 + srow) * K + swz4(srow, lane & 3) * 8;
    const u16* gB = Bt + (size_t)(n0 + srow) * K + swz4(srow, lane & 3) * 8;
    const int ldst = w * 512;                          // per-wave LDS dest offset

    f32x4 acc[4][4];
    #pragma unroll
    for (int i = 0; i < 4; ++i)
        #pragma unroll
        for (int j = 0; j < 4; ++j) acc[i][j] = (f32x4)0.0f;

    const int NT = K >> 5;

    // prologue: stage tile 0
    gload16(gA, As[0] + ldst);
    gload16(gA + (size_t)64 * K, As[0] + 64 * 32 + ldst);
    gload16(gB, Bs[0] + ldst);
    gload16(gB + (size_t)64 * K, Bs[0] + 64 * 32 + ldst);
    __syncthreads();                                   // drains vmcnt(0)

    for (int t = 0; t < NT; ++t) {
        const int cur = t & 1;
        if (t + 1 < NT) {                              // prefetch next tile
            const int k0 = (t + 1) * 32;
            gload16(gA + k0, As[cur ^ 1] + ldst);
            gload16(gA + k0 + (size_t)64 * K, As[cur ^ 1] + 64 * 32 + ldst);
            gload16(gB + k0, Bs[cur ^ 1] + ldst);
            gload16(gB + k0 + (size_t)64 * K, Bs[cur ^ 1] + 64 * 32 + ldst);
        }
        bf16x8 af[4], bfr[4];
        #pragma unroll
        for (int fi = 0; fi < 4; ++fi)
            af[fi] = *(const bf16x8*)&As[cur][(wm * 64 + fi * 16 + c) * 32 + (g ^ cs) * 8];
        #pragma unroll
        for (int fj = 0; fj < 4; ++fj)
            bfr[fj] = *(const bf16x8*)&Bs[cur][(wn * 64 + fj * 16 + c) * 32 + (g ^ cs) * 8];
        #pragma unroll
        for (int fi = 0; fi < 4; ++fi)
            #pragma unroll
            for (int fj = 0; fj < 4; ++fj)
                acc[fi][fj] = MFMA_BF16(af[fi], bfr[fj], acc[fi][fj]);
        __syncthreads();   // drains vmcnt(0) (prefetch landed) + read-safety
    }

    if (EPI == 0) {
        const int which = blockIdx.y / 3;            // N=1152, 384 per which
        u16* dst = (which == 0 ? qo : which == 1 ? ko : vo);
        #pragma unroll
        for (int fi = 0; fi < 4; ++fi) {
            #pragma unroll
            for (int r = 0; r < 4; ++r) {
                const int m = m0 + wm * 64 + fi * 16 + 4 * g + r;
                const int t = m & 511, bb = m >> 9;
                const float csn = cst[t], sn = snt[t];
                #pragma unroll
                for (int fj = 0; fj < 4; ++fj) {
                    const int n = n0 + wn * 64 + fj * 16 + c;
                    float v = acc[fi][fj][r] + bias[n];
                    const float vp = __shfl_xor(v, 1);
                    float ov;
                    if (which < 2)
                        ov = ((n & 1) == 0) ? csn * v - sn * vp : sn * vp + csn * v;
                    else
                        ov = v;
                    const float op = __shfl_xor(ov, 1);
                    if ((c & 1) == 0) {
                        const int rest = n - which * 384;
                        const int h = rest >> 6, d = rest & 63;   // d even
                        const u32 pk = (u32)f2bf(ov) | ((u32)f2bf(op) << 16);
                        *(u32*)&dst[(((size_t)bb * H_ + h) * T_ + t) * 64 + d] = pk;
                    }
                }
            }
        }
    } else if (EPI == 1) {
        #pragma unroll
        for (int fi = 0; fi < 4; ++fi) {
            #pragma unroll
            for (int r = 0; r < 4; ++r) {
                const int m = m0 + wm * 64 + fi * 16 + 4 * g + r;
                #pragma unroll
                for (int fj = 0; fj < 4; ++fj) {
                    const int n = n0 + wn * 64 + fj * 16 + c;
                    float v = acc[fi][fj][r] + bias[n] + res[(size_t)m * N + n];
                    outf[(size_t)m * N + n] = v;
                }
            }
        }
    } else {
        #pragma unroll
        for (int fi = 0; fi < 4; ++fi) {
            #pragma unroll
            for (int r = 0; r < 4; ++r) {
                const int m = m0 + wm * 64 + fi * 16 + 4 * g + r;
                #pragma unroll
                for (int fj = 0; fj < 4; ++fj) {
                    const int n = n0 + wn * 64 + fj * 16 + c;
                    float v = fmaxf(acc[fi][fj][r] + bias[n], 0.0f);
                    const float vn = __shfl_xor(v, 1);
                    if ((c & 1) == 0) {
                        const u32 pk = (u32)f2bf(v) | ((u32)f2bf(vn) << 16);
                        *(u32*)&outb[(size_t)m * N + n] = pk;
                    }
                }
            }
        }
    }
}

// ---------------------------------------------------------------------------
// Flash attention, bf16 MFMA.  1-D grid, XCD-clustered: all 8 q-tiles of one
// (b,h) run on the same XCD (shared K/V stays in that XCD's L2).
// 4 waves x 16 q-rows.  Async staging: issue K/V(kt+1) global->reg loads
// before computing kt; ds_write after the barrier (T14).
// V^T and P written as packed u32 (2-way bank aliasing = free).
// ---------------------------------------------------------------------------
#define KS_B(r, chB) ((r) * 176 + (chB) * 16)
#define VT_B(d, t)   ((d) * 176 + ((((t) >> 3) ^ ((d) & 7) ^ ((d) >> 3)) << 4) + (((t) & 7) << 1))

__global__ __launch_bounds__(256)
void attn_mfma(const u16* __restrict__ Q, const u16* __restrict__ K,
               const u16* __restrict__ V, u16* __restrict__ out, int cpx)
{
    __shared__ u16 Ks[64 * 88];
    __shared__ u16 Vt[64 * 88];
    __shared__ u16 Ps[4][16 * 88];

    // XCD-clustering: logical = (wg%8)*cpx + wg/8 ; hb major, qt minor
    const int wg = blockIdx.x;
    const int logical = (wg & 7) * cpx + (wg >> 3);
    const int qt = logical & 7;
    const int hb = logical >> 3;
    const int h = hb % H_, b = hb / H_;

    const int tid = threadIdx.x;
    const int w = tid >> 6, lane = tid & 63;
    const int c = lane & 15, g = lane >> 4;
    const int p2 = tid >> 3;          // row-pair index 0..31 (rows 2p2, 2p2+1)
    const int ch = tid & 7;           // 8-elem d-chunk
    const size_t base = ((size_t)b * H_ + h) * T_ * 64;
    const int qrow0 = qt * 64 + w * 16;
    const float scale = 0.05103103630798288f;   // 384^-0.5

    bf16x8 qf[2];
    #pragma unroll
    for (int kh = 0; kh < 2; ++kh)
        qf[kh] = *(const bf16x8*)&Q[base + (size_t)(qrow0 + c) * 64 + kh * 32 + g * 8];

    f32x4 O[4];
    float m_[4], l_[4];
    #pragma unroll
    for (int i = 0; i < 4; ++i) { O[i] = (f32x4)0.0f; m_[i] = -INFINITY; l_[i] = 0.0f; }

    u16* Pw = Ps[w];

    // prologue: stage tile 0 (reg -> LDS)
    {
        const size_t src = base + (size_t)(2 * p2) * 64 + ch * 8;
        short8 krA = *(const short8*)&K[src];
        short8 krB = *(const short8*)&K[src + 64];
        short8 vrA = *(const short8*)&V[src];
        short8 vrB = *(const short8*)&V[src + 64];
        *(short8*)((char*)Ks + KS_B(2 * p2, ch)) = krA;
        *(short8*)((char*)Ks + KS_B(2 * p2 + 1, ch)) = krB;
        #pragma unroll
        for (int j = 0; j < 8; ++j) {
            const int d = ch * 8 + j;
            const u32 pk = (u32)(u16)vrA[j] | ((u32)(u16)vrB[j] << 16);
            *(u32*)((char*)Vt + VT_B(d, 2 * p2)) = pk;
        }
    }
    __syncthreads();

    short8 krA, krB, vrA, vrB;
    for (int kt = 0; kt <= qt; ++kt) {
        if (kt < qt) {   // issue next tile's global loads early (latency hidden)
            const size_t src = base + (size_t)((kt + 1) * 64 + 2 * p2) * 64 + ch * 8;
            krA = *(const short8*)&K[src];
            krB = *(const short8*)&K[src + 64];
            vrA = *(const short8*)&V[src];
            vrB = *(const short8*)&V[src + 64];
        }

        // S = Q K^T : 4 col-frags x 2 k-halves
        f32x4 S[4];
        #pragma unroll
        for (int fc = 0; fc < 4; ++fc) {
            S[fc] = (f32x4)0.0f;
            #pragma unroll
            for (int kh = 0; kh < 2; ++kh) {
                bf16x8 kf = *(const bf16x8*)((char*)Ks + KS_B(fc * 16 + c, kh * 4 + g));
                S[fc] = MFMA_BF16(qf[kh], kf, S[fc]);
            }
        }

        // scale + causal mask + online softmax (rows shared by 16 lanes)
        const bool diag = (kt == qt);
        #pragma unroll
        for (int r = 0; r < 4; ++r) {
            const int qloc = w * 16 + 4 * g + r;
            float mx = -INFINITY;
            #pragma unroll
            for (int fc = 0; fc < 4; ++fc) {
                float sv = S[fc][r] * scale;
                if (diag && (fc * 16 + c > qloc)) sv = -INFINITY;
                S[fc][r] = sv;
                mx = fmaxf(mx, sv);
            }
            #pragma unroll
            for (int off = 1; off < 16; off <<= 1)
                mx = fmaxf(mx, __shfl_xor(mx, off, 16));
            const float mnew = fmaxf(m_[r], mx);
            const float corr = __expf(m_[r] - mnew);
            m_[r] = mnew;
            float su = 0.0f;
            #pragma unroll
            for (int fc = 0; fc < 4; ++fc) {
                const float p = __expf(S[fc][r] - mnew);
                S[fc][r] = p; su += p;
            }
            #pragma unroll
            for (int off = 1; off < 16; off <<= 1)
                su += __shfl_xor(su, off, 16);
            l_[r] = l_[r] * corr + su;
            #pragma unroll
            for (int fd = 0; fd < 4; ++fd) O[fd][r] *= corr;
        }

        // P -> per-wave LDS, packed u32 pairs (no cross-wave barrier needed)
        #pragma unroll
        for (int fc = 0; fc < 4; ++fc)
            #pragma unroll
            for (int r = 0; r < 4; ++r) {
                const float pv = S[fc][r];
                const float pn = __shfl_xor(pv, 1);
                if ((c & 1) == 0) {
                    const u32 pk = (u32)f2bf(pv) | ((u32)f2bf(pn) << 16);
                    *(u32*)((char*)Pw + (4 * g + r) * 176 + (fc * 16 + c) * 2) = pk;
                }
            }

        bf16x8 pa[2];
        #pragma unroll
        for (int kh = 0; kh < 2; ++kh)
            pa[kh] = *(const bf16x8*)((char*)Pw + c * 176 + kh * 64 + g * 16);
        #pragma unroll
        for (int fd = 0; fd < 4; ++fd) {
            const int d = fd * 16 + c;
            #pragma unroll
            for (int kh = 0; kh < 2; ++kh) {
                const int kb = kh * 4 + g;
                bf16x8 vf = *(const bf16x8*)((char*)Vt + d * 176 + (((kb) ^ (d & 7) ^ (d >> 3)) << 4));
                O[fd] = MFMA_BF16(pa[kh], vf, O[fd]);
            }
        }

        if (kt < qt) {   // commit prefetched tile to LDS
            __syncthreads();   // all waves done reading Ks/Vt
            *(short8*)((char*)Ks + KS_B(2 * p2, ch)) = krA;
            *(short8*)((char*)Ks + KS_B(2 * p2 + 1, ch)) = krB;
            #pragma unroll
            for (int j = 0; j < 8; ++j) {
                const int d = ch * 8 + j;
                const u32 pk = (u32)(u16)vrA[j] | ((u32)(u16)vrB[j] << 16);
                *(u32*)((char*)Vt + VT_B(d, 2 * p2)) = pk;
            }
            __syncthreads();   // new tile visible
        }
    }

    #pragma unroll
    for (int r = 0; r < 4; ++r) {
        const int t = qrow0 + 4 * g + r;
        const float inv = 1.0f / l_[r];
        const size_t o = ((size_t)b * T_ + t) * C_ + h * 64;
        #pragma unroll
        for (int fd = 0; fd < 4; ++fd)
            out[o + fd * 16 + c] = f2bf(O[fd][r] * inv);
    }
}

// ---------------------------------------------------------------------------
// LayerNorm over C=384, fp32 in, fp32 and/or bf16 out.  1 wave/row.
// ---------------------------------------------------------------------------
__global__ __launch_bounds__(256)
void ln_kernel(const float* __restrict__ in, const float* __restrict__ gam,
               const float* __restrict__ bta, float* __restrict__ outf,
               u16* __restrict__ outb)
{
    const int lane = threadIdx.x & 63;
    const int wv   = threadIdx.x >> 6;
    const size_t row = (size_t)blockIdx.x * 4 + wv;
    const float* x = in + row * C_;

    float vals[6];
    float s = 0.0f;
    #pragma unroll
    for (int i = 0; i < 6; ++i) { vals[i] = x[lane + i * 64]; s += vals[i]; }
    #pragma unroll
    for (int off = 1; off < 64; off <<= 1) s += __shfl_xor(s, off, 64);
    const float mean = s * (1.0f / 384.0f);

    float vs = 0.0f;
    #pragma unroll
    for (int i = 0; i < 6; ++i) { const float d = vals[i] - mean; vs += d * d; }
    #pragma unroll
    for (int off = 1; off < 64; off <<= 1) vs += __shfl_xor(vs, off, 64);
    const float inv = rsqrtf(vs * (1.0f / 384.0f) + 1e-5f);

    #pragma unroll
    for (int i = 0; i < 6; ++i) {
        const int cc = lane + i * 64;
        const float y = gam[cc] * (vals[i] - mean) * inv + bta[cc];
        if (outf) outf[row * C_ + cc] = y;
        if (outb) outb[row * C_ + cc] = f2bf(y);
    }
}

// ---------------------------------------------------------------------------
extern "C" void kernel_launch(void* const* d_in, const int* in_sizes, int n_in,
                              void* d_out, int out_size, void* d_ws, size_t ws_size,
                              hipStream_t stream)
{
    const float* x    = (const float*)d_in[0];
    const float* q1w  = (const float*)d_in[1];  const float* q1b = (const float*)d_in[2];
    const float* k1w  = (const float*)d_in[3];  const float* k1b = (const float*)d_in[4];
    const float* v1w  = (const float*)d_in[5];  const float* v1b = (const float*)d_in[6];
    const float* p1w  = (const float*)d_in[7];  const float* p1b = (const float*)d_in[8];
    const float* ln1g = (const float*)d_in[9];  const float* ln1b = (const float*)d_in[10];
    const float* q2w  = (const float*)d_in[11]; const float* q2b = (const float*)d_in[12];
    const float* k2w  = (const float*)d_in[13]; const float* k2b = (const float*)d_in[14];
    const float* v2w  = (const float*)d_in[15]; const float* v2b = (const float*)d_in[16];
    const float* p2w  = (const float*)d_in[17]; const float* p2b = (const float*)d_in[18];
    const float* ln2g = (const float*)d_in[19]; const float* ln2b = (const float*)d_in[20];
    const float* f1w  = (const float*)d_in[21]; const float* f1b = (const float*)d_in[22];
    const float* f2w  = (const float*)d_in[23]; const float* f2b = (const float*)d_in[24];
    const float* ln3g = (const float*)d_in[25]; const float* ln3b = (const float*)d_in[26];

    // ---- workspace: bf16 weights + fp32 tables + chunk slices ----
    const size_t WQKV = 1152 * 384, WP = 384 * 384, WF = 1536 * 384;
    u16* wq1 = (u16*)d_ws;
    u16* wq2 = wq1 + WQKV;
    u16* p1t = wq2 + WQKV;
    u16* p2t = p1t + WP;
    u16* f1t = p2t + WP;
    u16* f2t = f1t + WF;
    float* bq1 = (float*)(f2t + WF);
    float* bq2 = bq1 + 1152;
    float* cst = bq2 + 1152;
    float* snt = cst + 512;
    u16* chunkBase = (u16*)(snt + 512);
    const size_t fixedBytes = (size_t)((char*)chunkBase - (char*)d_ws);

    // 6 bf16 slices + 2 fp32 slices of Mc*C each = 20 B per element
    int CB = 64;
    while (CB > 1 && fixedBytes + 20ull * CB * T_ * C_ > ws_size) CB >>= 1;
    const size_t McC = (size_t)CB * T_ * C_;
    const int Mc = CB * T_;

    u16* sQ  = chunkBase;
    u16* sK  = sQ + McC;
    u16* sV  = sK + McC;
    u16* sAb = sV + McC;
    u16* sX  = sAb + McC;        // x-cast, then y1 bf16
    u16* sO2 = sX + McC;         // y2 bf16
    u16* tmp = sQ;               // FF intermediate overlays q,k,v,abuf
    float* bufF = (float*)(sO2 + McC);
    float* y1f  = bufF + McC;

    const dim3 blk(256);
    const int attnBlocks = 48 * CB;      // 8 qt * 6 h * CB
    const int cpx = 6 * CB;              // blocks per XCD chunk

    prep_kernel<<<dim3(2304, 7), blk, 0, stream>>>(
        q1w, k1w, v1w, q2w, k2w, v2w, p1w, p2w, f1w, f2w,
        q1b, k1b, v1b, q2b, k2b, v2b,
        wq1, wq2, p1t, p2t, f1t, f2t, bq1, bq2, cst, snt);

    for (int b0 = 0; b0 < B_; b0 += CB) {
        const float* xc = x + (size_t)b0 * T_ * C_;
        float*       oc = (float*)d_out + (size_t)b0 * T_ * C_;

        cast_kernel<<<dim3(2048), blk, 0, stream>>>(xc, sX, (int)(McC / 4));

        // ---- layer 1 ----
        gemm_mfma<0><<<dim3(Mc / 128, 9), blk, 0, stream>>>(sX, wq1, 384, bq1,
            nullptr, nullptr, nullptr, sQ, sK, sV, cst, snt, 1152);
        attn_mfma<<<dim3(attnBlocks), blk, 0, stream>>>(sQ, sK, sV, sAb, cpx);
        gemm_mfma<1><<<dim3(Mc / 128, 3), blk, 0, stream>>>(sAb, p1t, 384, p1b,
            xc, bufF, nullptr, nullptr, nullptr, nullptr, cst, snt, 384);
        ln_kernel<<<dim3(Mc / 4), blk, 0, stream>>>(bufF, ln1g, ln1b, y1f, sX);

        // ---- layer 2 ----
        gemm_mfma<0><<<dim3(Mc / 128, 9), blk, 0, stream>>>(sX, wq2, 384, bq2,
            nullptr, nullptr, nullptr, sQ, sK, sV, cst, snt, 1152);
        attn_mfma<<<dim3(attnBlocks), blk, 0, stream>>>(sQ, sK, sV, sAb, cpx);
        gemm_mfma<1><<<dim3(Mc / 128, 3), blk, 0, stream>>>(sAb, p2t, 384, p2b,
            y1f, bufF, nullptr, nullptr, nullptr, nullptr, cst, snt, 384);
        ln_kernel<<<dim3(Mc / 4), blk, 0, stream>>>(bufF, ln2g, ln2b, oc, sO2);

        // ---- feed-forward ----
        gemm_mfma<2><<<dim3(Mc / 128, 12), blk, 0, stream>>>(sO2, f1t, 384, f1b,
            nullptr, nullptr, tmp, nullptr, nullptr, nullptr, cst, snt, 1536);
        gemm_mfma<1><<<dim3(Mc / 128, 3), blk, 0, stream>>>(tmp, f2t, 1536, f2b,
            oc, bufF, nullptr, nullptr, nullptr, nullptr, cst, snt, 384);
        ln_kernel<<<dim3(Mc / 4), blk, 0, stream>>>(bufF, ln3g, ln3b, oc, nullptr);
    }
}